// Round 4
// baseline (1557.827 us; speedup 1.0000x reference)
//
#include <hip/hip_runtime.h>
#include <hip/hip_bf16.h>

#define DOUT 128
#define DIN  256
#define FO_ROWS 32

// ============================ CSR build =====================================

__global__ void hist_rows(const int* __restrict__ rows, int* __restrict__ cnt,
                          int nE) {
    int i = blockIdx.x * blockDim.x + threadIdx.x;
    if (i < nE) atomicAdd(&cnt[rows[i]], 1);
}

// Block-level inclusive scan of cnt -> row_ptr[i+1] (block-local), bsum[b].
__global__ void scan_blocks(const int* __restrict__ cnt, int* __restrict__ row_ptr,
                            int* __restrict__ bsum, int n) {
    __shared__ int buf[1024];
    int tid = threadIdx.x;
    int i = blockIdx.x * 1024 + tid;
    buf[tid] = (i < n) ? cnt[i] : 0;
    __syncthreads();
    for (int off = 1; off < 1024; off <<= 1) {
        int t = (tid >= off) ? buf[tid - off] : 0;
        __syncthreads();
        buf[tid] += t;
        __syncthreads();
    }
    if (i < n) row_ptr[i + 1] = buf[tid];
    if (tid == 1023) bsum[blockIdx.x] = buf[1023];
}

// Single small block: inclusive scan of block sums (nb <= 1024).
__global__ void scan_bsum(int* __restrict__ bsum, int nb) {
    __shared__ int buf[1024];
    int t = threadIdx.x;
    buf[t] = (t < nb) ? bsum[t] : 0;
    __syncthreads();
    for (int off = 1; off < 1024; off <<= 1) {
        int v = (t >= off) ? buf[t - off] : 0;
        __syncthreads();
        buf[t] += v;
        __syncthreads();
    }
    if (t < nb) bsum[t] = buf[t];
}

// Add block offsets in-place; derive cursor[i] = exclusive prefix.
__global__ void finalize_rowptr(const int* __restrict__ cnt,
                                const int* __restrict__ bsum,
                                int* __restrict__ row_ptr,
                                int* __restrict__ cursor, int n) {
    int tid = threadIdx.x;
    int i = blockIdx.x * 1024 + tid;
    if (i == 0) row_ptr[0] = 0;
    if (i >= n) return;
    int off = (blockIdx.x == 0) ? 0 : bsum[blockIdx.x - 1];
    int incl = row_ptr[i + 1] + off;
    row_ptr[i + 1] = incl;
    cursor[i] = incl - cnt[i];
}

// Scatter edges into CSR order; (col,val) packed into one 8B store.
__global__ void scatter_edges(const int* __restrict__ rows,
                              const int* __restrict__ cols,
                              const float* __restrict__ vals,
                              int* __restrict__ cursor,
                              int2* __restrict__ ecv, int nE) {
    int i = blockIdx.x * blockDim.x + threadIdx.x;
    if (i >= nE) return;
    int slot = atomicAdd(&cursor[rows[i]], 1);
    ecv[slot] = make_int2(cols[i], __float_as_int(vals[i]));
}

// ============================ SPMM (CSR) ====================================
// One wave per row; lane i owns cols {2i,2i+1}. Every S element written once.
__global__ void spmm_csr(const int* __restrict__ row_ptr,
                         const int2* __restrict__ ecv,
                         const float* __restrict__ h,
                         float* __restrict__ S, int n) {
    int row = blockIdx.x * 4 + (threadIdx.x >> 6);
    int lane = threadIdx.x & 63;
    if (row >= n) return;
    int beg = row_ptr[row], end = row_ptr[row + 1];
    float2 acc = {0.f, 0.f};
#pragma unroll 4
    for (int e = beg; e < end; ++e) {
        int2 cv = ecv[e];
        float2 hv = ((const float2*)(h + (size_t)cv.x * DOUT))[lane];
        float v = __int_as_float(cv.y);
        acc.x += v * hv.x;
        acc.y += v * hv.y;
    }
    ((float2*)(S + (size_t)row * DOUT))[lane] = acc;
}

// ==================== fallback: atomic SPMM (round-2 path) ==================
__global__ void spmm_atomic(const int* __restrict__ rows,
                            const int* __restrict__ cols,
                            const float* __restrict__ vals,
                            const float* __restrict__ h,
                            float* __restrict__ S, int nEdges) {
    int wave = (int)((blockIdx.x * blockDim.x + threadIdx.x) >> 6);
    int lane = threadIdx.x & 63;
    if (wave >= nEdges) return;
    int r = rows[wave];
    int c = cols[wave];
    float v = vals[wave];
    float2 hv = ((const float2*)(h + (size_t)c * DOUT))[lane];
    float* srow = S + (size_t)r * DOUT;
    atomicAdd(srow + 2 * lane,     v * hv.x);
    atomicAdd(srow + 2 * lane + 1, v * hv.y);
}

// ============================ fused epilogue ================================
// out[r,:] = relu(x[r,:] @ W + S[r,:] @ V), in place on d_out (S == pre-out).
// 32 rows per 256-thread block. x/S tiles staged TRANSPOSED in LDS so the
// inner loop is broadcast ds_read_b128 (all lanes same address) + FMA; W/V
// come from global (L2-resident, traffic amortized 32x vs 1-row blocks).
// In-place safe: all reads of this block's rows happen before the barrier.
#define XT_STRIDE 36   // pad 32->36 so &xsT[k][16] stays 16B-aligned, banks ok
__global__ __launch_bounds__(256) void fused_out2(const float* __restrict__ x,
                                                  const float* __restrict__ W,
                                                  const float* __restrict__ V,
                                                  float* __restrict__ out, int N) {
    __shared__ float xsT[DIN][XT_STRIDE];   // 36.9 KB
    __shared__ float ssT[DOUT][XT_STRIDE];  // 18.4 KB
    int r0 = blockIdx.x * FO_ROWS;
    int t = threadIdx.x;
    int col = t & 127;
    int g = t >> 7;            // 0..1 -> rows g*16 .. g*16+15

    // ---- stage x tile (32 rows x 256) transposed; 8 float4 per thread ----
    {
        int row = t >> 3;                         // 0..31
        int kb = t & 7;
        int srow = min(r0 + row, N - 1);          // clamp: OOB-safe loads
        const float4* xr = (const float4*)(x + (size_t)srow * DIN);
        for (int i = 0; i < 8; ++i) {
            int k4 = kb + 8 * i;                  // 0..63
            float4 v4 = xr[k4];
            int k = 4 * k4;
            xsT[k][row] = v4.x; xsT[k+1][row] = v4.y;
            xsT[k+2][row] = v4.z; xsT[k+3][row] = v4.w;
        }
        // ---- stage S tile (32 rows x 128) transposed; 4 float4 per thread ----
        const float4* sr = (const float4*)(out + (size_t)srow * DOUT);
        for (int i = 0; i < 4; ++i) {
            int k4 = kb + 8 * i;                  // 0..31
            float4 v4 = sr[k4];
            int k = 4 * k4;
            ssT[k][row] = v4.x; ssT[k+1][row] = v4.y;
            ssT[k+2][row] = v4.z; ssT[k+3][row] = v4.w;
        }
    }
    __syncthreads();

    float acc[16];
#pragma unroll
    for (int j = 0; j < 16; ++j) acc[j] = 0.f;
    int rb = g * 16;

#pragma unroll 2
    for (int k = 0; k < DIN; ++k) {
        float w = W[k * DOUT + col];
        const float4* xp = (const float4*)&xsT[k][rb];
        float4 a0 = xp[0], a1 = xp[1], a2 = xp[2], a3 = xp[3];
        acc[0]  += w * a0.x; acc[1]  += w * a0.y; acc[2]  += w * a0.z; acc[3]  += w * a0.w;
        acc[4]  += w * a1.x; acc[5]  += w * a1.y; acc[6]  += w * a1.z; acc[7]  += w * a1.w;
        acc[8]  += w * a2.x; acc[9]  += w * a2.y; acc[10] += w * a2.z; acc[11] += w * a2.w;
        acc[12] += w * a3.x; acc[13] += w * a3.y; acc[14] += w * a3.z; acc[15] += w * a3.w;
    }
#pragma unroll 2
    for (int k = 0; k < DOUT; ++k) {
        float v = V[k * DOUT + col];
        const float4* sp = (const float4*)&ssT[k][rb];
        float4 a0 = sp[0], a1 = sp[1], a2 = sp[2], a3 = sp[3];
        acc[0]  += v * a0.x; acc[1]  += v * a0.y; acc[2]  += v * a0.z; acc[3]  += v * a0.w;
        acc[4]  += v * a1.x; acc[5]  += v * a1.y; acc[6]  += v * a1.z; acc[7]  += v * a1.w;
        acc[8]  += v * a2.x; acc[9]  += v * a2.y; acc[10] += v * a2.z; acc[11] += v * a2.w;
        acc[12] += v * a3.x; acc[13] += v * a3.y; acc[14] += v * a3.z; acc[15] += v * a3.w;
    }

#pragma unroll
    for (int j = 0; j < 16; ++j) {
        int r = r0 + rb + j;
        if (r < N) out[(size_t)r * DOUT + col] = fmaxf(acc[j], 0.f);
    }
}

extern "C" void kernel_launch(void* const* d_in, const int* in_sizes, int n_in,
                              void* d_out, int out_size, void* d_ws, size_t ws_size,
                              hipStream_t stream) {
    const float* x    = (const float*)d_in[0];
    const float* h    = (const float*)d_in[1];
    const int*   rows = (const int*)d_in[2];
    const int*   cols = (const int*)d_in[3];
    const float* vals = (const float*)d_in[4];
    const float* W    = (const float*)d_in[5];
    const float* V    = (const float*)d_in[6];
    // d_in[7] (alpha): softmax over size-1 axis == 1 -> dead.

    int nE = in_sizes[2];              // D*E = 6.4M
    int N  = in_sizes[1] / DOUT;       // 50000
    float* out = (float*)d_out;

    int nScanBlocks = (N + 1023) / 1024;   // 49

    // Workspace: cnt[N] | row_ptr[N+1] | cursor[N] | bsum[1024] | ecv[nE int2]
    size_t need = (size_t)(3 * N + 1 + 1024) * 4 + (size_t)nE * 8;

    if (ws_size >= need) {
        int*  cnt     = (int*)d_ws;
        int*  row_ptr = cnt + N;
        int*  cursor  = row_ptr + (N + 1);
        int*  bsum    = cursor + N;
        int2* ecv     = (int2*)(bsum + 1024);

        hipMemsetAsync(cnt, 0, (size_t)N * 4, stream);
        hist_rows<<<(nE + 255) / 256, 256, 0, stream>>>(rows, cnt, nE);
        scan_blocks<<<nScanBlocks, 1024, 0, stream>>>(cnt, row_ptr, bsum, N);
        scan_bsum<<<1, 1024, 0, stream>>>(bsum, nScanBlocks);
        finalize_rowptr<<<nScanBlocks, 1024, 0, stream>>>(cnt, bsum, row_ptr, cursor, N);
        scatter_edges<<<(nE + 255) / 256, 256, 0, stream>>>(rows, cols, vals,
                                                            cursor, ecv, nE);
        spmm_csr<<<(N + 3) / 4, 256, 0, stream>>>(row_ptr, ecv, h, out, N);
    } else {
        hipMemsetAsync(out, 0, (size_t)N * DOUT * 4, stream);
        spmm_atomic<<<(nE + 3) / 4, 256, 0, stream>>>(rows, cols, vals, h, out, nE);
    }

    fused_out2<<<(N + FO_ROWS - 1) / FO_ROWS, 256, 0, stream>>>(x, W, V, out, N);
}